// Round 2
// baseline (274.580 us; speedup 1.0000x reference)
//
#include <hip/hip_runtime.h>

// Problem constants (from setup_inputs): B=16, C=256, H=96, W=96, REP_K=3
#define B_    16
#define C_    256
#define HH    96
#define WW    96
#define W4    24          // WW / 4 float4 columns
#define TYN   8           // h-groups
#define HPT   12          // h values per thread (HH / TYN)
#define TPB   (W4 * TYN)  // 192 threads = 3 waves

// Weight-window element access: e in [0,23], compile-time constant after unroll,
// so the ternaries fold and ww stays in registers.
#define WGET(e) ( ((e)&3)==0 ? ww[(e)>>2].x \
                : ((e)&3)==1 ? ww[(e)>>2].y \
                : ((e)&3)==2 ? ww[(e)>>2].z \
                :              ww[(e)>>2].w )

// One half-group of FMAs: 6 j-steps x 12 accumulators x float4.
// Weight for (j = jj + RBASE + r, row h0+i) is window element 12 + RBASE + r - i.
#define FMA_HALF(RBASE, XBUF)                                     \
    _Pragma("unroll")                                             \
    for (int r = 0; r < 6; ++r) {                                 \
        _Pragma("unroll")                                         \
        for (int i = 0; i < HPT; ++i) {                           \
            const float wv = WGET(12 + (RBASE) + r - i);          \
            acc[i].x += wv * XBUF[r].x;                           \
            acc[i].y += wv * XBUF[r].y;                           \
            acc[i].z += wv * XBUF[r].z;                           \
            acc[i].w += wv * XBUF[r].w;                           \
        }                                                         \
    }

// Fused circular depthwise conv along H:
// out[b,c,h,w] = sum_j eff_w[c,(j-h)%96] * (x+meta_pe)[b,c,j,w] + bias[c]
// eff_w[c,k] = weight[c,k] + (k<3 ? rep_weight[c,k] : 0)
__global__ __launch_bounds__(TPB, 3) void fused_circ_conv(
    const float* __restrict__ x,
    const float* __restrict__ meta_pe,
    const float* __restrict__ weight,
    const float* __restrict__ bias,
    const float* __restrict__ rep_weight,
    float* __restrict__ out)
{
    __shared__ __align__(16) float sX[HH * WW];     // 36 KB tile, row-major [h][w], meta_pe folded in
    __shared__ __align__(16) float sWext[2 * HH];   // eff_w doubled: sWext[t] = eff_w[t % 96]

    const int tid = threadIdx.x;
    const int blk = blockIdx.x;       // blk = b*256 + c
    const int c = blk & (C_ - 1);

    const size_t base = (size_t)blk * (HH * WW);
    const float4* __restrict__ xg4 = (const float4*)(x + base);

    const int tx = tid % W4;      // w-quad
    const int ty = tid / W4;      // h-group
    const int h0 = ty * HPT;

    // --- stage effective weights (192 entries, one per thread) ---
    {
        int k = (tid < HH) ? tid : (tid - HH);
        float wv = weight[c * HH + k];
        if (k < 3) wv += rep_weight[c * 3 + k];
        sWext[tid] = wv;
    }

    // --- stage X tile with meta_pe added (2304 float4 = 192 threads x 12) ---
    {
        float4* sX4 = (float4*)sX;
        const float* mp = meta_pe + c * HH;
#pragma unroll
        for (int r = 0; r < 12; ++r) {
            int i = tid + TPB * r;
            float4 v = xg4[i];
            float m = mp[ty + 8 * r];      // row h = i/24 = tid/24 + 8r
            v.x += m; v.y += m; v.z += m; v.w += m;
            sX4[i] = v;
        }
    }
    __syncthreads();

    float4 acc[HPT];
#pragma unroll
    for (int i = 0; i < HPT; ++i) acc[i] = make_float4(0.f, 0.f, 0.f, 0.f);

    // LDS access bases. (84 - h0) is a multiple of 12 -> 16B aligned for float4.
    const float4* __restrict__ xq = (const float4*)sX + tx;           // xq[j*W4] = X[j][quad tx]
    const float4* __restrict__ w4 = (const float4*)(sWext + (84 - h0));

    // Register state:
    //  ww[0..5]  : 24-float weight window; element t = sWext[84 + 12g - h0 + t]
    //              -> weight for (j=12g+r, row h0+i) is element 12 + r - i (in [1,23])
    //  wnxt[0..2]: prefetched new quads of next group's window
    //  xA/xB     : half-group (6 j-steps) of X quads, double-buffered
    float4 ww[6], wnxt[3], xA[6], xB[6];

#pragma unroll
    for (int q = 0; q < 6; ++q) ww[q] = w4[q];           // window for group 0
#pragma unroll
    for (int t = 0; t < 6; ++t) xA[t] = xq[t * W4];      // j = 0..5

#pragma unroll 1
    for (int g = 0; g < 7; ++g) {        // groups 0..6 (group 7 peeled, no prefetch)
        // issue loads for this group's second half (used ~576 issue-cycles later)
#pragma unroll
        for (int t = 0; t < 6; ++t) xB[t] = xq[(g * 12 + 6 + t) * W4];
        // issue next group's new weight quads (used at end of this group)
#pragma unroll
        for (int q = 0; q < 3; ++q) wnxt[q] = w4[3 * g + 6 + q];

        FMA_HALF(0, xA)                  // j = 12g .. 12g+5 (xA resident: loaded last group)

        // prefetch next group's first half: j = 12g+12 .. 12g+17
#pragma unroll
        for (int t = 0; t < 6; ++t) xA[t] = xq[(g * 12 + 12 + t) * W4];

        FMA_HALF(6, xB)                  // j = 12g+6 .. 12g+11

        // rotate window: [0..2] <- [3..5], [3..5] <- prefetched next quads
#pragma unroll
        for (int q = 0; q < 3; ++q) { ww[q] = ww[q + 3]; ww[q + 3] = wnxt[q]; }
    }

    // --- peeled final group g=7 (jj=84): xA holds j=84..89 from last prefetch ---
#pragma unroll
    for (int t = 0; t < 6; ++t) xB[t] = xq[(90 + t) * W4];
    FMA_HALF(0, xA)
    FMA_HALF(6, xB)

    // --- epilogue: add bias, store coalesced ---
    const float bv = bias[c];
    float4* og4 = (float4*)(out + base);
#pragma unroll
    for (int i = 0; i < HPT; ++i) {
        float4 v = acc[i];
        v.x += bv; v.y += bv; v.z += bv; v.w += bv;
        og4[(h0 + i) * W4 + tx] = v;
    }
}

extern "C" void kernel_launch(void* const* d_in, const int* in_sizes, int n_in,
                              void* d_out, int out_size, void* d_ws, size_t ws_size,
                              hipStream_t stream) {
    const float* x          = (const float*)d_in[0];
    const float* meta_pe    = (const float*)d_in[1];
    const float* weight     = (const float*)d_in[2];
    const float* bias       = (const float*)d_in[3];
    const float* rep_weight = (const float*)d_in[4];
    float* out = (float*)d_out;

    fused_circ_conv<<<dim3(B_ * C_), dim3(TPB), 0, stream>>>(
        x, meta_pe, weight, bias, rep_weight, out);
}

// Round 3
// 267.650 us; speedup vs baseline: 1.0259x; 1.0259x over previous
//
#include <hip/hip_runtime.h>

// Problem constants (from setup_inputs): B=16, C=256, H=96, W=96, REP_K=3
#define B_    16
#define C_    256
#define HH    96
#define WW    96
#define WQ    24          // float4 quads per full row (96/4)
#define TW4   8           // quads per tile (tile width 32 floats)
#define NS    3           // W-tiles per (b,c) image
#define TYN   24          // h-groups per block
#define HPT   4           // h rows per thread
#define TPB   (TW4 * TYN) // 192 threads = 3 waves

// Weight-window element access: e in [1,15], compile-time constant after
// unroll, so the ternaries fold and wq stays in registers.
#define WGET(e) ( ((e)&3)==0 ? wq[(e)>>2].x \
                : ((e)&3)==1 ? wq[(e)>>2].y \
                : ((e)&3)==2 ? wq[(e)>>2].z \
                :              wq[(e)>>2].w )

// Fused circular depthwise conv along H:
// out[b,c,h,w] = sum_j eff_w[c,(j-h)%96] * (x+meta_pe)[b,c,j,w] + bias[c]
// eff_w[c,k] = weight[c,k] + (k<3 ? rep_weight[c,k] : 0)
//
// Tile = 96 rows x 32 cols of one (b,c) image -> 12.75 KB LDS/block,
// 8 blocks/CU resident (24 waves, 75% occ) so staging of some blocks
// overlaps compute of others (the round-2 bottleneck was phase
// serialization at 4 blocks/CU).
__global__ __launch_bounds__(TPB, 6) void fused_circ_conv(
    const float* __restrict__ x,
    const float* __restrict__ meta_pe,
    const float* __restrict__ weight,
    const float* __restrict__ bias,
    const float* __restrict__ rep_weight,
    float* __restrict__ out)
{
    __shared__ __align__(16) float sX[HH * TW4 * 4];  // 12 KB tile [row][0..31], meta_pe folded in
    __shared__ __align__(16) float sWx[2 * HH];       // eff_w doubled: sWx[u] = eff_w[u % 96]

    const int tid = threadIdx.x;
    const int blk = blockIdx.x;       // blk = (b*256 + c)*3 + s
    const int bc  = blk / NS;         // b*256 + c
    const int s   = blk - bc * NS;    // W-tile index 0..2
    const int c   = bc & (C_ - 1);

    const int tx = tid % TW4;         // w-quad within tile
    const int ty = tid / TW4;         // h-group, 0..23
    const int h0 = ty * HPT;

    const size_t base = (size_t)bc * (HH * WW);
    const float4* __restrict__ xg4 = (const float4*)(x + base) + TW4 * s;

    // --- stage effective weights (192 entries, one per thread) ---
    {
        int k = (tid < HH) ? tid : (tid - HH);
        float wv = weight[c * HH + k];
        if (k < 3) wv += rep_weight[c * 3 + k];
        sWx[tid] = wv;
    }

    // --- stage X tile with meta_pe added (768 float4 = 192 threads x 4) ---
    {
        float4* sX4 = (float4*)sX;
        const float* mp = meta_pe + c * HH;
#pragma unroll
        for (int r = 0; r < 4; ++r) {
            // linear tile quad i = tid + 192r; row = ty + 24r, qcol = tx
            float4 v = xg4[(ty + TYN * r) * WQ + tx];
            float m = mp[ty + TYN * r];
            v.x += m; v.y += m; v.z += m; v.w += m;
            sX4[tid + TPB * r] = v;
        }
    }
    __syncthreads();

    float4 acc[HPT];
#pragma unroll
    for (int i = 0; i < HPT; ++i) acc[i] = make_float4(0.f, 0.f, 0.f, 0.f);

    // x reads: 8 distinct quads per j (broadcast over ty) = 32 consecutive
    // bank-words -> conflict-free.
    const float4* __restrict__ xq = (const float4*)sX + tx;
    // weight window for group g: W_g[t] = sWx[92 - h0 + 12g + t], t in [0,16)
    //   -> weight for (j=12g+r, row h0+i) is W_g[4 + r - i]
    //      (since 92 + 12g - h0 + 4 + r - i == 96 + j - h0 - i == (j-h)+96).
    // Quad base (92-h0)/4 = 23-ty; 8 distinct ty per wave -> 32 consecutive
    // bank-words -> conflict-free. Max float index 191-h0 <= 191.
    const float4* __restrict__ wqb = (const float4*)sWx + (23 - ty);

#pragma unroll 1
    for (int g = 0; g < 8; ++g) {
        float4 wq[4];
#pragma unroll
        for (int q = 0; q < 4; ++q) wq[q] = wqb[3 * g + q];
#pragma unroll
        for (int r = 0; r < 12; ++r) {
            float4 xv = xq[(12 * g + r) * TW4];
#pragma unroll
            for (int i = 0; i < HPT; ++i) {
                const float wv = WGET(4 + r - i);   // e in [1,15]
                acc[i].x += wv * xv.x;
                acc[i].y += wv * xv.y;
                acc[i].z += wv * xv.z;
                acc[i].w += wv * xv.w;
            }
        }
    }

    // --- epilogue: add bias, store coalesced ---
    const float bv = bias[c];
    float4* og4 = (float4*)(out + base) + TW4 * s;
#pragma unroll
    for (int i = 0; i < HPT; ++i) {
        float4 v = acc[i];
        v.x += bv; v.y += bv; v.z += bv; v.w += bv;
        og4[(h0 + i) * WQ + tx] = v;
    }
}

extern "C" void kernel_launch(void* const* d_in, const int* in_sizes, int n_in,
                              void* d_out, int out_size, void* d_ws, size_t ws_size,
                              hipStream_t stream) {
    const float* x          = (const float*)d_in[0];
    const float* meta_pe    = (const float*)d_in[1];
    const float* weight     = (const float*)d_in[2];
    const float* bias       = (const float*)d_in[3];
    const float* rep_weight = (const float*)d_in[4];
    float* out = (float*)d_out;

    fused_circ_conv<<<dim3(B_ * C_ * NS), dim3(TPB), 0, stream>>>(
        x, meta_pe, weight, bias, rep_weight, out);
}

// Round 4
// 267.126 us; speedup vs baseline: 1.0279x; 1.0020x over previous
//
#include <hip/hip_runtime.h>

// Problem constants: B=16, C=256, H=96, W=96, REP_K=3
#define B_   16
#define C_   256
#define HH   96
#define WW   96
#define TPB  192   // 3 waves; wave wv owns n-tile (cols w = wv*32 .. wv*32+31)

typedef _Float16 half8 __attribute__((ext_vector_type(8)));
typedef float   f32x16 __attribute__((ext_vector_type(16)));

// Circulant MFMA formulation: per (b,c) image,
//   out[h,w] = sum_j effw[(j-h) mod 96] * (x[j,w] + pe[j]) + bias
// = D = A(96x96 circulant of effw) x B(96x96 image cols), M=h, K=j, N=w.
// f16 two-term split: v = vh + vl (vh=f16(v), vl=f16(v-vh)); keep hh+lh+hl
// products (drop ll ~ 2^-23) -> ~fp32 accuracy, fp32 MFMA accumulate.
//
// B-fragments stream straight from GLOBAL (8 consecutive j at fixed w per
// lane: each load instr covers exactly two full 128B lines) -> no X staging,
// no transpose, no main-loop barriers. LDS = 1.1 KB weight/PE tables only.
__global__ __launch_bounds__(TPB, 4) void fused_circ_conv_mfma(
    const float* __restrict__ x,
    const float* __restrict__ meta_pe,
    const float* __restrict__ weight,
    const float* __restrict__ bias,
    const float* __restrict__ rep_weight,
    float* __restrict__ out)
{
    __shared__ float sW[2 * HH];   // doubled effective weights: sW[t] = effw[t % 96]
    __shared__ float sPE[HH];      // meta_pe[c][:]

    const int tid = threadIdx.x;
    const int blk = blockIdx.x;          // b*256 + c
    const int c   = blk & (C_ - 1);
    const size_t base = (size_t)blk * (HH * WW);

    // --- stage weight + pe tables (one barrier total) ---
    {
        int k = (tid < HH) ? tid : (tid - HH);
        float wv = weight[c * HH + k];
        if (k < 3) wv += rep_weight[c * 3 + k];
        sW[tid] = wv;
        if (tid < HH) sPE[tid] = meta_pe[c * HH + tid];
    }
    __syncthreads();

    const int lane = tid & 63;
    const int wvid = tid >> 6;           // wave id = n-tile 0..2
    const int r32  = lane & 31;          // A-row / B-col within 32
    const int g    = lane >> 5;          // k-half 0/1

    // ---- B operand: column w = wvid*32 + r32, all 96 rows, streamed from HBM ----
    // lane element (kt, e): j = kt*16 + g*8 + e
    const float* __restrict__ xcol = x + base + (wvid * 32 + r32);
    float bx[48];
#pragma unroll
    for (int kt = 0; kt < 6; ++kt)
#pragma unroll
        for (int e = 0; e < 8; ++e)
            bx[kt * 8 + e] = xcol[(kt * 16 + g * 8 + e) * WW];

    half8 bh[6], bl[6];
#pragma unroll
    for (int kt = 0; kt < 6; ++kt) {
#pragma unroll
        for (int e = 0; e < 8; ++e) {
            float v = bx[kt * 8 + e] + sPE[kt * 16 + g * 8 + e];  // pe: broadcast read
            _Float16 h = (_Float16)v;
            bh[kt][e] = h;
            bl[kt][e] = (_Float16)(v - (float)h);
        }
    }

    const float bv = bias[c];

#pragma unroll 1
    for (int m = 0; m < 3; ++m) {        // m-tile: output rows m*32 .. m*32+31
        f32x16 acc;
#pragma unroll
        for (int i = 0; i < 16; ++i) acc[i] = 0.f;

#pragma unroll
        for (int kt = 0; kt < 6; ++kt) {
            // A-frag: A[row=r32][k=g*8+e] = sW[96 + j - h], j = kt*16+g*8+e, h = m*32+r32.
            // Float index range [1,191] -> in bounds; lanes read 32 consecutive
            // (descending) words -> conflict-free (2-way across g, free).
            const float* wp = sW + (96 + kt * 16 + g * 8 - m * 32 - r32);
            half8 ah, al;
#pragma unroll
            for (int e = 0; e < 8; ++e) {
                float w_ = wp[e];
                _Float16 h = (_Float16)w_;
                ah[e] = h;
                al[e] = (_Float16)(w_ - (float)h);
            }
            acc = __builtin_amdgcn_mfma_f32_32x32x16_f16(ah, bh[kt], acc, 0, 0, 0);
            acc = __builtin_amdgcn_mfma_f32_32x32x16_f16(al, bh[kt], acc, 0, 0, 0);
            acc = __builtin_amdgcn_mfma_f32_32x32x16_f16(ah, bl[kt], acc, 0, 0, 0);
        }

        // C/D layout (guide-verified): col = lane&31, row = (reg&3)+8*(reg>>2)+4*(lane>>5)
        float* __restrict__ op = out + base + (wvid * 32 + r32);
#pragma unroll
        for (int reg = 0; reg < 16; ++reg) {
            int row = m * 32 + (reg & 3) + 8 * (reg >> 2) + 4 * g;
            op[row * WW] = acc[reg] + bv;   // 2x128B segments per store instr
        }
    }
}

extern "C" void kernel_launch(void* const* d_in, const int* in_sizes, int n_in,
                              void* d_out, int out_size, void* d_ws, size_t ws_size,
                              hipStream_t stream) {
    const float* x          = (const float*)d_in[0];
    const float* meta_pe    = (const float*)d_in[1];
    const float* weight     = (const float*)d_in[2];
    const float* bias       = (const float*)d_in[3];
    const float* rep_weight = (const float*)d_in[4];
    float* out = (float*)d_out;

    fused_circ_conv_mfma<<<dim3(B_ * C_), dim3(TPB), 0, stream>>>(
        x, meta_pe, weight, bias, rep_weight, out);
}

// Round 6
// 263.978 us; speedup vs baseline: 1.0402x; 1.0119x over previous
//
#include <hip/hip_runtime.h>

// Problem constants: B=16, C=256, H=96, W=96, REP_K=3
#define B_   16
#define C_   256
#define HH   96
#define WW   96
#define TPB  192   // 3 waves; wave wv owns cols w = wv*32 .. wv*32+31

typedef _Float16 half8 __attribute__((ext_vector_type(8)));
typedef float   f32x16 __attribute__((ext_vector_type(16)));

// Circulant MFMA formulation: per (b,c) image,
//   out[h,w] = sum_j effw[(j-h) mod 96] * (x[j,w] + pe[j]) + bias
// A = 96x96 circulant of effw (M=h), B = image (K=j, N=w).
// f16 two-term split (hh+lh+hl products) -> ~fp32 accuracy (validated R4).
//
// R4 was latency-bound: compiler sank 48 scalar global loads -> ~3KB/wave MLP
// -> 2.4 TB/s. Fix: per-wave LDS staging via 12 global_load_dwordx4
// (12 KB in flight per wave), B-frags via conflict-free ds_read_b32.
// A is circulant: only 6 distinct A-fragments (frag(m,kt)=frag(0,(kt-2m)%6)).
__global__ __launch_bounds__(TPB) void fused_circ_conv_mfma(
    const float* __restrict__ x,
    const float* __restrict__ meta_pe,
    const float* __restrict__ weight,
    const float* __restrict__ bias,
    const float* __restrict__ rep_weight,
    float* __restrict__ out)
{
    __shared__ __align__(16) float sX[3][HH][32];   // 36 KB, per-wave 12KB slices
    __shared__ float sW[2 * HH];                    // doubled effw

    const int tid  = threadIdx.x;
    const int blk  = blockIdx.x;          // b*256 + c
    const int c    = blk & (C_ - 1);
    const size_t base = (size_t)blk * (HH * WW);

    const int lane = tid & 63;
    const int wv   = tid >> 6;            // wave id = n-tile 0..2
    const int r32  = lane & 31;           // A-row / B-col within 32
    const int g    = lane >> 5;           // k-half 0/1

    // --- stage effective weights (192 entries, one per thread) ---
    {
        int k = (tid < HH) ? tid : (tid - HH);
        float w_ = weight[c * HH + k];
        if (k < 3) w_ += rep_weight[c * 3 + k];
        sW[tid] = w_;
    }

    // --- stage this wave's 32-col slice of (x + pe): 12 x dwordx4, 12 KB in flight ---
    {
        const int q  = lane & 7;          // col-quad within slice
        const int jr = lane >> 3;         // row within 8-row group
        const float* __restrict__ xg = x + base + wv * 32 + q * 4;
        const float* __restrict__ pe = meta_pe + c * HH;
        float* __restrict__ sxw = &sX[wv][0][0];
#pragma unroll
        for (int t = 0; t < 12; ++t) {
            const int j = t * 8 + jr;
            float4 v = *(const float4*)(xg + (size_t)j * WW);
            float m = pe[j];
            v.x += m; v.y += m; v.z += m; v.w += m;
            *(float4*)(sxw + j * 32 + q * 4) = v;   // 1KB contiguous per instr
        }
    }
    __syncthreads();

    // --- A fragments: 6 distinct (circulant, 16-step shifts) ---
    // frag s element (g,e): effw[(s*16 + g*8 + e - r32) mod 96] = sW[96 + s*16 + g*8 + e - r32]
    // float index range [65,191] -> in bounds; lanes: 32 consecutive words x2 -> conflict-free.
    half8 ah[6], al[6];
#pragma unroll
    for (int s = 0; s < 6; ++s) {
        const float* wp = sW + (96 + s * 16 + g * 8 - r32);
#pragma unroll
        for (int e = 0; e < 8; ++e) {
            float w_ = wp[e];
            _Float16 h = (_Float16)w_;
            ah[s][e] = h;
            al[s][e] = (_Float16)(w_ - (float)h);
        }
    }

    // --- B fragments from LDS (row j = kt*16+g*8+e, col r32): 2-way reads, free ---
    half8 bh[6], bl[6];
    {
        const float* __restrict__ sxw = &sX[wv][0][0];
#pragma unroll
        for (int kt = 0; kt < 6; ++kt) {
#pragma unroll
            for (int e = 0; e < 8; ++e) {
                float v = sxw[(kt * 16 + g * 8 + e) * 32 + r32];
                _Float16 h = (_Float16)v;
                bh[kt][e] = h;
                bl[kt][e] = (_Float16)(v - (float)h);
            }
        }
    }

    const float bv = bias[c];
    float* __restrict__ op = out + base + (wv * 32 + r32);

    // --- 3 m-tiles x 6 k-tiles x 3 split-terms = 54 MFMA ---
#pragma unroll
    for (int m = 0; m < 3; ++m) {
        f32x16 acc;
#pragma unroll
        for (int i = 0; i < 16; ++i) acc[i] = 0.f;
#pragma unroll
        for (int kt = 0; kt < 6; ++kt) {
            const int s = (kt + 6 - 2 * m) % 6;   // compile-time after unroll
            acc = __builtin_amdgcn_mfma_f32_32x32x16_f16(ah[s], bh[kt], acc, 0, 0, 0);
            acc = __builtin_amdgcn_mfma_f32_32x32x16_f16(al[s], bh[kt], acc, 0, 0, 0);
            acc = __builtin_amdgcn_mfma_f32_32x32x16_f16(ah[s], bl[kt], acc, 0, 0, 0);
        }
        // C/D layout: col = lane&31, row = (reg&3)+8*(reg>>2)+4*(lane>>5)  (R4-verified)
#pragma unroll
        for (int reg = 0; reg < 16; ++reg) {
            int row = m * 32 + (reg & 3) + 8 * (reg >> 2) + 4 * g;
            op[(size_t)row * WW] = acc[reg] + bv;
        }
    }
}

extern "C" void kernel_launch(void* const* d_in, const int* in_sizes, int n_in,
                              void* d_out, int out_size, void* d_ws, size_t ws_size,
                              hipStream_t stream) {
    const float* x          = (const float*)d_in[0];
    const float* meta_pe    = (const float*)d_in[1];
    const float* weight     = (const float*)d_in[2];
    const float* bias       = (const float*)d_in[3];
    const float* rep_weight = (const float*)d_in[4];
    float* out = (float*)d_out;

    fused_circ_conv_mfma<<<dim3(B_ * C_), dim3(TPB), 0, stream>>>(
        x, meta_pe, weight, bias, rep_weight, out);
}